// Round 8
// baseline (611.812 us; speedup 1.0000x reference)
//
#include <hip/hip_runtime.h>
#include <hip/hip_bf16.h>

typedef __hip_bfloat16 bf16;

#define NVX 117000
#define NVR 117120         // rows padded to multiple of 128
#define NEX 468000
#define EMB 300
#define STR 320            // padded K/row stride for bf16 node buffers (pads zeroed)
#define NPAD 384           // padded N for node GEMM (3 tiles of 128)
#define IN_DIM 768
#define BATCH 4096
#define HID 500
#define FCK 1088           // FC1 K: [H2 row 0..319 | input 0..767]
#define HPAD 512           // FC hidden padded
#define NB 458             // scan blocks: ceil(NVX/256)

// k_prep linear segments
#define PRE_H   (NVR*80)
#define PRE_W12 (NPAD*STR)
#define PRE_WA  (HPAD*FCK)
#define PRE_WB  (HPAD*HPAD)
#define PRE_TOT (PRE_H + 2*PRE_W12 + PRE_WA + PRE_WB)

typedef __attribute__((ext_vector_type(8))) short frag8;   // 8 bf16 (4 VGPRs)
typedef __attribute__((ext_vector_type(4))) float f32x4;   // 4 fp32 acc

__device__ __forceinline__ float sigmoidf_(float x){ return 1.0f/(1.0f + __expf(-x)); }
__device__ __forceinline__ float bfs2f(short s){
  return __uint_as_float(((unsigned int)(unsigned short)s) << 16);
}
__device__ __forceinline__ short f2bfs(float f){
  bf16 b = __float2bfloat16(f);
  return *(short*)&b;
}

__device__ __forceinline__ void gload_lds16(const bf16* g, bf16* l){
  __builtin_amdgcn_global_load_lds((const __attribute__((address_space(1))) void*)g,
                                   (__attribute__((address_space(3))) void*)l, 16, 0, 0);
}

// ---------------- graph preprocessing ----------------

__global__ void k_deg(const int* __restrict__ erow, int* __restrict__ deg){
  int i = blockIdx.x*blockDim.x + threadIdx.x;
  if (i < NEX) atomicAdd(&deg[erow[i]], 1);
}

// per-256-block degree sums (+ dinv folded in)
__global__ __launch_bounds__(256) void k_partsum(const int* __restrict__ deg,
                                                 float* __restrict__ dinv,
                                                 int* __restrict__ bsum){
  __shared__ int s[256];
  int t = threadIdx.x;
  int i = blockIdx.x*256 + t;
  int d = (i < NVX) ? deg[i] : 0;
  if (i < NVX) dinv[i] = d > 0 ? rsqrtf((float)d) : 0.0f;
  s[t] = d;
  __syncthreads();
  #pragma unroll
  for (int off=128; off; off>>=1){
    if (t < off) s[t] += s[t+off];
    __syncthreads();
  }
  if (t == 0) bsum[blockIdx.x] = s[0];
}

__global__ __launch_bounds__(512) void k_scanb(const int* __restrict__ bsum,
                                               int* __restrict__ boff,
                                               int* __restrict__ rowptr){
  __shared__ int s[512];
  int t = threadIdx.x;
  int v = (t < NB) ? bsum[t] : 0;
  s[t] = v; __syncthreads();
  #pragma unroll
  for (int off=1; off<512; off<<=1){
    int u = (t>=off) ? s[t-off] : 0;
    __syncthreads();
    s[t] += u;
    __syncthreads();
  }
  if (t < NB) boff[t] = s[t] - v;
  if (t == 511) rowptr[NVX] = s[511];
}

__global__ __launch_bounds__(256) void k_writeptr(const int* __restrict__ deg,
                                                  const int* __restrict__ boff,
                                                  int* __restrict__ rowptr,
                                                  int* __restrict__ cursor){
  __shared__ int s[256];
  int t = threadIdx.x;
  int i = blockIdx.x*256 + t;
  int v = (i < NVX) ? deg[i] : 0;
  s[t] = v; __syncthreads();
  #pragma unroll
  for (int off=1; off<256; off<<=1){
    int u = (t>=off) ? s[t-off] : 0;
    __syncthreads();
    s[t] += u;
    __syncthreads();
  }
  if (i < NVX){
    int e = boff[blockIdx.x] + s[t] - v;
    rowptr[i] = e;
    cursor[i] = e;
  }
}

__global__ void k_scatter(const int* __restrict__ erow, const int* __restrict__ ecol,
                          const float* __restrict__ dinv, int* __restrict__ cursor,
                          int* __restrict__ ccol, float* __restrict__ cval){
  int i = blockIdx.x*blockDim.x + threadIdx.x;
  if (i < NEX){
    int r = erow[i], c = ecol[i];
    int p = atomicAdd(&cursor[r], 1);
    ccol[p] = c;
    cval[p] = dinv[r]*dinv[c];
  }
}

// ---------------- one prep kernel: H0->bf16 Xs, 4 weight transposes ----------------
// linear index over segments: [prepH | Wt1 | Wt2 | Wat | Wbt]
// Wat k-mapping: k<300 -> Wa[k], 300..319 -> 0, 320.. -> Wa[k-20]  (FC1 A = [H2row|input])

__global__ __launch_bounds__(256) void k_prep(const float* __restrict__ H0,
                                              const float* __restrict__ W1,
                                              const float* __restrict__ W2,
                                              const float* __restrict__ Wa,
                                              const float* __restrict__ Wb,
                                              bf16* __restrict__ Xs,
                                              bf16* __restrict__ Wt1,
                                              bf16* __restrict__ Wt2,
                                              bf16* __restrict__ Wat,
                                              bf16* __restrict__ Wbt){
  long i = (long)blockIdx.x*256 + threadIdx.x;
  if (i < PRE_H){
    int r = (int)(i / 80), g = (int)(i % 80);
    int c = g*4;
    short4 o;
    if (r < NVX && c < EMB){
      float4 v = *(const float4*)(H0 + (size_t)r*EMB + c);
      o.x = f2bfs(v.x); o.y = f2bfs(v.y); o.z = f2bfs(v.z); o.w = f2bfs(v.w);
    } else {
      o.x = o.y = o.z = o.w = 0;
    }
    *(short4*)(Xs + (size_t)r*STR + c) = o;
    return;
  }
  i -= PRE_H;
  if (i < 2*PRE_W12){
    const float* W = (i < PRE_W12) ? W1 : W2;
    bf16* o = (i < PRE_W12) ? Wt1 : Wt2;
    int j = (int)((i < PRE_W12) ? i : i - PRE_W12);
    int n = j / STR, k = j % STR;
    float v = (n < EMB && k < EMB) ? W[k*EMB + n] : 0.0f;
    o[j] = __float2bfloat16(v);
    return;
  }
  i -= 2*PRE_W12;
  if (i < PRE_WA){
    int n = (int)(i / FCK), k = (int)(i % FCK);
    float v = 0.0f;
    if (n < HID){
      if (k < EMB)        v = Wa[(size_t)k*HID + n];
      else if (k >= STR)  v = Wa[(size_t)(k-(STR-EMB))*HID + n];
    }
    Wat[i] = __float2bfloat16(v);
    return;
  }
  i -= PRE_WA;
  if (i < PRE_WB){
    int n = (int)(i / HPAD), k = (int)(i % HPAD);
    float v = (n < HID && k < HID) ? Wb[(size_t)k*HID + n] : 0.0f;
    Wbt[i] = __float2bfloat16(v);
  }
}

// ---------------- spmm (vectorized): Y[v,:] = sum_e val * X[col(e),:] ----------------
// wave per row; lanes 0..39 each own 8 contiguous cols (16 B vector load per edge).

__global__ __launch_bounds__(256) void k_spmm_v(const int* __restrict__ rowptr,
                                                const int* __restrict__ ccol,
                                                const float* __restrict__ cval,
                                                const bf16* __restrict__ X,
                                                bf16* __restrict__ Y){
  int w = (int)((blockIdx.x*blockDim.x + threadIdx.x) >> 6);
  int lane = threadIdx.x & 63;
  if (w >= NVR || lane >= 40) return;
  float acc[8] = {0.f,0.f,0.f,0.f,0.f,0.f,0.f,0.f};
  if (w < NVX){
    int e0 = rowptr[w], e1 = rowptr[w+1];
    int e = e0;
    for (; e + 3 < e1; e += 4){
      float v0 = cval[e], v1 = cval[e+1], v2 = cval[e+2], v3 = cval[e+3];
      frag8 x0 = *(const frag8*)(X + (size_t)ccol[e  ]*STR + lane*8);
      frag8 x1 = *(const frag8*)(X + (size_t)ccol[e+1]*STR + lane*8);
      frag8 x2 = *(const frag8*)(X + (size_t)ccol[e+2]*STR + lane*8);
      frag8 x3 = *(const frag8*)(X + (size_t)ccol[e+3]*STR + lane*8);
      #pragma unroll
      for (int j=0;j<8;++j)
        acc[j] += v0*bfs2f(x0[j]) + v1*bfs2f(x1[j]) + v2*bfs2f(x2[j]) + v3*bfs2f(x3[j]);
    }
    for (; e < e1; ++e){
      float v0 = cval[e];
      frag8 x0 = *(const frag8*)(X + (size_t)ccol[e]*STR + lane*8);
      #pragma unroll
      for (int j=0;j<8;++j) acc[j] += v0*bfs2f(x0[j]);
    }
  }
  frag8 o;
  #pragma unroll
  for (int j=0;j<8;++j) o[j] = f2bfs(acc[j]);
  *(frag8*)(Y + (size_t)w*STR + lane*8) = o;
}

// ---------------- node GEMM (MFMA): C = sigmoid(A @ W), pads zeroed ----------------
// 1-D grid NVR/128; inner loop over 3 n-tiles so the A-stripe is L2-hot on re-stage.

__global__ __launch_bounds__(256) void k_gemm_node(const bf16* __restrict__ A,
                                                   const bf16* __restrict__ Wt,
                                                   bf16* __restrict__ C){
  __shared__ bf16 As[128*32];
  __shared__ bf16 Bs[128*32];
  const int tid  = threadIdx.x;
  const int wv   = tid >> 6;
  const int lane = tid & 63;
  const int row0 = blockIdx.x * 128;
  const int wm = wv & 1, wn = wv >> 1;
  const int srow = lane >> 2;
  const int schk = lane & 3;
  const int fr = lane & 15, fq = lane >> 4;

  for (int nt = 0; nt < 3; ++nt){
    const int n0 = nt * 128;
    f32x4 acc[4][4];
    #pragma unroll
    for (int i=0;i<4;++i)
      #pragma unroll
      for (int j=0;j<4;++j) acc[i][j] = (f32x4)(0.0f);

    for (int k0 = 0; k0 < STR; k0 += 32){
      const bf16* ag = A + (size_t)(row0 + wv*16 + srow)*STR + k0 + schk*8;
      gload_lds16(ag,           As + wv*512 + lane*8);
      gload_lds16(ag + 64*STR,  As + 2048 + wv*512 + lane*8);
      const bf16* bg = Wt + (size_t)(n0 + wv*16 + srow)*STR + k0 + schk*8;
      gload_lds16(bg,           Bs + wv*512 + lane*8);
      gload_lds16(bg + 64*STR,  Bs + 2048 + wv*512 + lane*8);
      __syncthreads();
      frag8 a[4], b[4];
      #pragma unroll
      for (int mi=0;mi<4;++mi)
        a[mi] = *(const frag8*)(As + (wm*64 + mi*16 + fr)*32 + fq*8);
      #pragma unroll
      for (int ni=0;ni<4;++ni)
        b[ni] = *(const frag8*)(Bs + (wn*64 + ni*16 + fr)*32 + fq*8);
      #pragma unroll
      for (int mi=0;mi<4;++mi)
        #pragma unroll
        for (int ni=0;ni<4;++ni)
          acc[mi][ni] = __builtin_amdgcn_mfma_f32_16x16x32_bf16(a[mi], b[ni], acc[mi][ni], 0, 0, 0);
      __syncthreads();
    }

    // C/D layout col=lane&15, row=(lane>>4)*4+reg  [m89/m91-verified]
    #pragma unroll
    for (int mi=0;mi<4;++mi){
      int row = row0 + wm*64 + mi*16 + fq*4;
      #pragma unroll
      for (int ni=0;ni<4;++ni){
        int col = n0 + wn*64 + ni*16 + fr;
        if (col < STR){
          bf16* cp = C + (size_t)row*STR + col;
          #pragma unroll
          for (int r=0;r<4;++r){
            float v = (col < EMB) ? sigmoidf_(acc[mi][ni][r]) : 0.0f;
            cp[(size_t)r*STR] = __float2bfloat16(v);
          }
        }
      }
    }
  }
}

// ---------------- FC1 (fused gather): h1 = sigmoid([H2[node], input] @ Wa + ba) ----------------

__global__ __launch_bounds__(256) void k_fc1g(const bf16* __restrict__ H2,
                                              const int* __restrict__ node,
                                              const float* __restrict__ input,
                                              const bf16* __restrict__ Wat,
                                              const float* __restrict__ ba,
                                              bf16* __restrict__ h1){
  __shared__ bf16 As[128*32];
  __shared__ bf16 Bs[128*32];
  const int tid  = threadIdx.x;
  const int wv   = tid >> 6;
  const int lane = tid & 63;
  const int row0 = blockIdx.y * 128;
  const int n0   = blockIdx.x * 128;
  const int wm = wv & 1, wn = wv >> 1;
  const int srow = lane >> 2;
  const int schk = lane & 3;
  const int fr = lane & 15, fq = lane >> 4;

  const int nlo = node[row0 + wv*16 + srow];
  const int nhi = node[row0 + 64 + wv*16 + srow];

  f32x4 acc[4][4];
  #pragma unroll
  for (int i=0;i<4;++i)
    #pragma unroll
    for (int j=0;j<4;++j) acc[i][j] = (f32x4)(0.0f);

  for (int k0 = 0; k0 < FCK; k0 += 32){
    if (k0 < STR){
      gload_lds16(H2 + (size_t)nlo*STR + k0 + schk*8, As + wv*512 + lane*8);
      gload_lds16(H2 + (size_t)nhi*STR + k0 + schk*8, As + 2048 + wv*512 + lane*8);
    } else {
      int c = k0 - STR + schk*8;
      int m0 = wv*16 + srow;
      float4 u0 = *(const float4*)(input + (size_t)(row0+m0)*IN_DIM + c);
      float4 u1 = *(const float4*)(input + (size_t)(row0+m0)*IN_DIM + c + 4);
      frag8 t0;
      t0[0]=f2bfs(u0.x); t0[1]=f2bfs(u0.y); t0[2]=f2bfs(u0.z); t0[3]=f2bfs(u0.w);
      t0[4]=f2bfs(u1.x); t0[5]=f2bfs(u1.y); t0[6]=f2bfs(u1.z); t0[7]=f2bfs(u1.w);
      *(frag8*)(As + m0*32 + schk*8) = t0;
      int m1 = 64 + wv*16 + srow;
      float4 u2 = *(const float4*)(input + (size_t)(row0+m1)*IN_DIM + c);
      float4 u3 = *(const float4*)(input + (size_t)(row0+m1)*IN_DIM + c + 4);
      frag8 t1;
      t1[0]=f2bfs(u2.x); t1[1]=f2bfs(u2.y); t1[2]=f2bfs(u2.z); t1[3]=f2bfs(u2.w);
      t1[4]=f2bfs(u3.x); t1[5]=f2bfs(u3.y); t1[6]=f2bfs(u3.z); t1[7]=f2bfs(u3.w);
      *(frag8*)(As + m1*32 + schk*8) = t1;
    }
    gload_lds16(Wat + (size_t)(n0 + wv*16 + srow)*FCK + k0 + schk*8, Bs + wv*512 + lane*8);
    gload_lds16(Wat + (size_t)(n0 + 64 + wv*16 + srow)*FCK + k0 + schk*8, Bs + 2048 + wv*512 + lane*8);
    __syncthreads();
    frag8 a[4], b[4];
    #pragma unroll
    for (int mi=0;mi<4;++mi)
      a[mi] = *(const frag8*)(As + (wm*64 + mi*16 + fr)*32 + fq*8);
    #pragma unroll
    for (int ni=0;ni<4;++ni)
      b[ni] = *(const frag8*)(Bs + (wn*64 + ni*16 + fr)*32 + fq*8);
    #pragma unroll
    for (int mi=0;mi<4;++mi)
      #pragma unroll
      for (int ni=0;ni<4;++ni)
        acc[mi][ni] = __builtin_amdgcn_mfma_f32_16x16x32_bf16(a[mi], b[ni], acc[mi][ni], 0, 0, 0);
    __syncthreads();
  }

  #pragma unroll
  for (int mi=0;mi<4;++mi){
    int row = row0 + wm*64 + mi*16 + fq*4;
    #pragma unroll
    for (int ni=0;ni<4;++ni){
      int col = n0 + wn*64 + ni*16 + fr;
      float bv = (col < HID) ? ba[col] : 0.0f;
      bf16* cp = h1 + (size_t)row*HPAD + col;
      #pragma unroll
      for (int r=0;r<4;++r)
        cp[(size_t)r*HPAD] = __float2bfloat16(sigmoidf_(acc[mi][ni][r] + bv));
    }
  }
}

// ---------------- FC2+FC3 fused: out = sigmoid(h1@Wb+bb) @ Wc + bc ----------------
// per-row partial dot with Wc reduced across fr lanes (shfl_xor<16), one f32 atomicAdd
// per (row, j, block-col). bc added once by the n0==0 / wn==0 owner. out pre-zeroed.

__global__ __launch_bounds__(256) void k_fc2o(const bf16* __restrict__ A,
                                              const bf16* __restrict__ B,
                                              const float* __restrict__ bb,
                                              const float* __restrict__ Wc,
                                              const float* __restrict__ bc,
                                              float* __restrict__ out){
  __shared__ bf16 As[128*32];
  __shared__ bf16 Bs[128*32];
  const int tid  = threadIdx.x;
  const int wv   = tid >> 6;
  const int lane = tid & 63;
  const int row0 = blockIdx.y * 128;
  const int n0   = blockIdx.x * 128;
  const int wm = wv & 1, wn = wv >> 1;
  const int srow = lane >> 2;
  const int schk = lane & 3;
  const int fr = lane & 15, fq = lane >> 4;

  f32x4 acc[4][4];
  #pragma unroll
  for (int i=0;i<4;++i)
    #pragma unroll
    for (int j=0;j<4;++j) acc[i][j] = (f32x4)(0.0f);

  for (int k0 = 0; k0 < HPAD; k0 += 32){
    const bf16* ag = A + (size_t)(row0 + wv*16 + srow)*HPAD + k0 + schk*8;
    gload_lds16(ag,            As + wv*512 + lane*8);
    gload_lds16(ag + 64*HPAD,  As + 2048 + wv*512 + lane*8);
    const bf16* bg = B + (size_t)(n0 + wv*16 + srow)*HPAD + k0 + schk*8;
    gload_lds16(bg,            Bs + wv*512 + lane*8);
    gload_lds16(bg + 64*HPAD,  Bs + 2048 + wv*512 + lane*8);
    __syncthreads();
    frag8 a[4], b[4];
    #pragma unroll
    for (int mi=0;mi<4;++mi)
      a[mi] = *(const frag8*)(As + (wm*64 + mi*16 + fr)*32 + fq*8);
    #pragma unroll
    for (int ni=0;ni<4;++ni)
      b[ni] = *(const frag8*)(Bs + (wn*64 + ni*16 + fr)*32 + fq*8);
    #pragma unroll
    for (int mi=0;mi<4;++mi)
      #pragma unroll
      for (int ni=0;ni<4;++ni)
        acc[mi][ni] = __builtin_amdgcn_mfma_f32_16x16x32_bf16(a[mi], b[ni], acc[mi][ni], 0, 0, 0);
    __syncthreads();
  }

  #pragma unroll
  for (int mi=0;mi<4;++mi){
    #pragma unroll
    for (int r=0;r<4;++r){
      int row = row0 + wm*64 + mi*16 + fq*4 + r;
      float s0 = 0.0f, s1 = 0.0f;
      #pragma unroll
      for (int ni=0;ni<4;++ni){
        int col = n0 + wn*64 + ni*16 + fr;
        if (col < HID){
          float v = sigmoidf_(acc[mi][ni][r] + bb[col]);
          s0 += v * Wc[col*2+0];
          s1 += v * Wc[col*2+1];
        }
      }
      #pragma unroll
      for (int off=1; off<16; off<<=1){
        s0 += __shfl_xor(s0, off);
        s1 += __shfl_xor(s1, off);
      }
      if (fr == 0){
        if (n0 == 0 && wn == 0){ s0 += bc[0]; s1 += bc[1]; }
        atomicAdd(out + (size_t)row*2 + 0, s0);
        atomicAdd(out + (size_t)row*2 + 1, s1);
      }
    }
  }
}

// ---------------- launch ----------------

extern "C" void kernel_launch(void* const* d_in, const int* in_sizes, int n_in,
                              void* d_out, int out_size, void* d_ws, size_t ws_size,
                              hipStream_t stream){
  const float* input = (const float*)d_in[0];
  const int*   node  = (const int*)d_in[1];
  const int*   erow  = (const int*)d_in[2];
  const int*   ecol  = (const int*)d_in[3];
  const float* H0    = (const float*)d_in[4];
  const float* W1    = (const float*)d_in[5];
  const float* W2    = (const float*)d_in[6];
  const float* Wa    = (const float*)d_in[7];
  const float* ba    = (const float*)d_in[8];
  const float* Wb    = (const float*)d_in[9];
  const float* bb    = (const float*)d_in[10];
  const float* Wc    = (const float*)d_in[11];
  const float* bc    = (const float*)d_in[12];

  char* p = (char*)d_ws;
  auto alloc = [&](size_t bytes)->char*{ char* r = p; p += (bytes + 255) & ~(size_t)255; return r; };
  int*   deg    = (int*)  alloc((size_t)NVX*4);
  float* dinv   = (float*)alloc((size_t)NVX*4);
  int*   rowptr = (int*)  alloc((size_t)(NVX+1)*4);
  int*   cursor = (int*)  alloc((size_t)NVX*4);
  int*   bsum   = (int*)  alloc((size_t)NB*4);
  int*   boff   = (int*)  alloc((size_t)NB*4);
  int*   ccol   = (int*)  alloc((size_t)NEX*4);
  float* cval   = (float*)alloc((size_t)NEX*4);
  bf16*  Xs     = (bf16*) alloc((size_t)NVR*STR*2);   // H0 bf16, later reused as H2
  bf16*  G      = (bf16*) alloc((size_t)NVR*STR*2);   // spmm output
  bf16*  Hb     = (bf16*) alloc((size_t)NVR*STR*2);   // H1
  bf16*  Wt1    = (bf16*) alloc((size_t)NPAD*STR*2);
  bf16*  Wt2    = (bf16*) alloc((size_t)NPAD*STR*2);
  bf16*  Wat    = (bf16*) alloc((size_t)HPAD*FCK*2);
  bf16*  Wbt    = (bf16*) alloc((size_t)HPAD*HPAD*2);
  bf16*  h1     = (bf16*) alloc((size_t)BATCH*HPAD*2);

  hipMemsetAsync(deg, 0, (size_t)NVX*4, stream);
  hipMemsetAsync(d_out, 0, (size_t)out_size*4, stream);
  k_deg     <<<(NEX+255)/256, 256, 0, stream>>>(erow, deg);
  k_partsum <<<NB, 256, 0, stream>>>(deg, dinv, bsum);
  k_scanb   <<<1, 512, 0, stream>>>(bsum, boff, rowptr);
  k_writeptr<<<NB, 256, 0, stream>>>(deg, boff, rowptr, cursor);
  k_scatter <<<(NEX+255)/256, 256, 0, stream>>>(erow, ecol, dinv, cursor, ccol, cval);
  k_prep    <<<(PRE_TOT+255)/256, 256, 0, stream>>>(H0, W1, W2, Wa, Wb, Xs, Wt1, Wt2, Wat, Wbt);

  // layer 1: H1 = sigmoid((LM @ H0) @ W1)
  k_spmm_v   <<<NVR/4, 256, 0, stream>>>(rowptr, ccol, cval, Xs, G);
  k_gemm_node<<<NVR/128, 256, 0, stream>>>(G, Wt1, Hb);
  // layer 2: H2 = sigmoid((LM @ H1) @ W2)   (H2 reuses Xs)
  k_spmm_v   <<<NVR/4, 256, 0, stream>>>(rowptr, ccol, cval, Hb, G);
  k_gemm_node<<<NVR/128, 256, 0, stream>>>(G, Wt2, Xs);

  // FC stack (FC3 fused into FC2 epilogue)
  k_fc1g<<<dim3(HPAD/128, BATCH/128), 256, 0, stream>>>(Xs, node, input, Wat, ba, h1);
  k_fc2o<<<dim3(HPAD/128, BATCH/128), 256, 0, stream>>>(h1, Wbt, bb, Wc, bc, (float*)d_out);
}

// Round 9
// 588.368 us; speedup vs baseline: 1.0398x; 1.0398x over previous
//
#include <hip/hip_runtime.h>
#include <hip/hip_bf16.h>

typedef __hip_bfloat16 bf16;

#define NVX 117000
#define NVR 117120         // rows padded to multiple of 128
#define NEX 468000
#define EMB 300
#define STR 320            // padded K/row stride for bf16 node buffers (pads zeroed)
#define NPAD 384           // padded N for node GEMM (3 tiles of 128)
#define IN_DIM 768
#define BATCH 4096
#define HID 500
#define FCK 1088           // FC1 K: [H2 row 0..319 | input 0..767]
#define HPAD 512           // FC hidden padded
#define NB 458             // scan blocks: ceil(NVX/256)

// k_prep linear segments
#define PRE_H   (NVR*80)
#define PRE_W12 (NPAD*STR)
#define PRE_WA  (HPAD*FCK)
#define PRE_WB  (HPAD*HPAD)
#define PRE_TOT (PRE_H + 2*PRE_W12 + PRE_WA + PRE_WB)

typedef __attribute__((ext_vector_type(8))) short frag8;   // 8 bf16 (4 VGPRs)
typedef __attribute__((ext_vector_type(4))) float f32x4;   // 4 fp32 acc

__device__ __forceinline__ float sigmoidf_(float x){ return 1.0f/(1.0f + __expf(-x)); }
__device__ __forceinline__ float bfs2f(short s){
  return __uint_as_float(((unsigned int)(unsigned short)s) << 16);
}
__device__ __forceinline__ short f2bfs(float f){
  bf16 b = __float2bfloat16(f);
  return *(short*)&b;
}

__device__ __forceinline__ void gload_lds16(const bf16* g, bf16* l){
  __builtin_amdgcn_global_load_lds((const __attribute__((address_space(1))) void*)g,
                                   (__attribute__((address_space(3))) void*)l, 16, 0, 0);
}

// ---------------- graph preprocessing ----------------

__global__ void k_deg(const int* __restrict__ erow, int* __restrict__ deg){
  int i = blockIdx.x*blockDim.x + threadIdx.x;
  if (i < NEX) atomicAdd(&deg[erow[i]], 1);
}

// per-256-block degree sums (+ dinv folded in)
__global__ __launch_bounds__(256) void k_partsum(const int* __restrict__ deg,
                                                 float* __restrict__ dinv,
                                                 int* __restrict__ bsum){
  __shared__ int s[256];
  int t = threadIdx.x;
  int i = blockIdx.x*256 + t;
  int d = (i < NVX) ? deg[i] : 0;
  if (i < NVX) dinv[i] = d > 0 ? rsqrtf((float)d) : 0.0f;
  s[t] = d;
  __syncthreads();
  #pragma unroll
  for (int off=128; off; off>>=1){
    if (t < off) s[t] += s[t+off];
    __syncthreads();
  }
  if (t == 0) bsum[blockIdx.x] = s[0];
}

__global__ __launch_bounds__(512) void k_scanb(const int* __restrict__ bsum,
                                               int* __restrict__ boff,
                                               int* __restrict__ rowptr){
  __shared__ int s[512];
  int t = threadIdx.x;
  int v = (t < NB) ? bsum[t] : 0;
  s[t] = v; __syncthreads();
  #pragma unroll
  for (int off=1; off<512; off<<=1){
    int u = (t>=off) ? s[t-off] : 0;
    __syncthreads();
    s[t] += u;
    __syncthreads();
  }
  if (t < NB) boff[t] = s[t] - v;
  if (t == 511) rowptr[NVX] = s[511];
}

__global__ __launch_bounds__(256) void k_writeptr(const int* __restrict__ deg,
                                                  const int* __restrict__ boff,
                                                  int* __restrict__ rowptr,
                                                  int* __restrict__ cursor){
  __shared__ int s[256];
  int t = threadIdx.x;
  int i = blockIdx.x*256 + t;
  int v = (i < NVX) ? deg[i] : 0;
  s[t] = v; __syncthreads();
  #pragma unroll
  for (int off=1; off<256; off<<=1){
    int u = (t>=off) ? s[t-off] : 0;
    __syncthreads();
    s[t] += u;
    __syncthreads();
  }
  if (i < NVX){
    int e = boff[blockIdx.x] + s[t] - v;
    rowptr[i] = e;
    cursor[i] = e;
  }
}

__global__ void k_scatter(const int* __restrict__ erow, const int* __restrict__ ecol,
                          const float* __restrict__ dinv, int* __restrict__ cursor,
                          int* __restrict__ ccol, float* __restrict__ cval){
  int i = blockIdx.x*blockDim.x + threadIdx.x;
  if (i < NEX){
    int r = erow[i], c = ecol[i];
    int p = atomicAdd(&cursor[r], 1);
    ccol[p] = c;
    cval[p] = dinv[r]*dinv[c];
  }
}

// ---------------- one prep kernel: H0->bf16 Xs, 4 weight transposes ----------------
// linear index over segments: [prepH | Wt1 | Wt2 | Wat | Wbt]
// Wat k-mapping: k<300 -> Wa[k], 300..319 -> 0, 320.. -> Wa[k-20]  (FC1 A = [H2row|input])

__global__ __launch_bounds__(256) void k_prep(const float* __restrict__ H0,
                                              const float* __restrict__ W1,
                                              const float* __restrict__ W2,
                                              const float* __restrict__ Wa,
                                              const float* __restrict__ Wb,
                                              bf16* __restrict__ Xs,
                                              bf16* __restrict__ Wt1,
                                              bf16* __restrict__ Wt2,
                                              bf16* __restrict__ Wat,
                                              bf16* __restrict__ Wbt){
  long i = (long)blockIdx.x*256 + threadIdx.x;
  if (i < PRE_H){
    int r = (int)(i / 80), g = (int)(i % 80);
    int c = g*4;
    short4 o;
    if (r < NVX && c < EMB){
      float4 v = *(const float4*)(H0 + (size_t)r*EMB + c);
      o.x = f2bfs(v.x); o.y = f2bfs(v.y); o.z = f2bfs(v.z); o.w = f2bfs(v.w);
    } else {
      o.x = o.y = o.z = o.w = 0;
    }
    *(short4*)(Xs + (size_t)r*STR + c) = o;
    return;
  }
  i -= PRE_H;
  if (i < 2*PRE_W12){
    const float* W = (i < PRE_W12) ? W1 : W2;
    bf16* o = (i < PRE_W12) ? Wt1 : Wt2;
    int j = (int)((i < PRE_W12) ? i : i - PRE_W12);
    int n = j / STR, k = j % STR;
    float v = (n < EMB && k < EMB) ? W[k*EMB + n] : 0.0f;
    o[j] = __float2bfloat16(v);
    return;
  }
  i -= 2*PRE_W12;
  if (i < PRE_WA){
    int n = (int)(i / FCK), k = (int)(i % FCK);
    float v = 0.0f;
    if (n < HID){
      if (k < EMB)        v = Wa[(size_t)k*HID + n];
      else if (k >= STR)  v = Wa[(size_t)(k-(STR-EMB))*HID + n];
    }
    Wat[i] = __float2bfloat16(v);
    return;
  }
  i -= PRE_WA;
  if (i < PRE_WB){
    int n = (int)(i / HPAD), k = (int)(i % HPAD);
    float v = (n < HID && k < HID) ? Wb[(size_t)k*HID + n] : 0.0f;
    Wbt[i] = __float2bfloat16(v);
  }
}

// ---------------- spmm (vectorized): Y[v,:] = sum_e val * X[col(e),:] ----------------
// wave per row; lanes 0..39 each own 8 contiguous cols (16 B vector load per edge).

__global__ __launch_bounds__(256) void k_spmm_v(const int* __restrict__ rowptr,
                                                const int* __restrict__ ccol,
                                                const float* __restrict__ cval,
                                                const bf16* __restrict__ X,
                                                bf16* __restrict__ Y){
  int w = (int)((blockIdx.x*blockDim.x + threadIdx.x) >> 6);
  int lane = threadIdx.x & 63;
  if (w >= NVR || lane >= 40) return;
  float acc[8] = {0.f,0.f,0.f,0.f,0.f,0.f,0.f,0.f};
  if (w < NVX){
    int e0 = rowptr[w], e1 = rowptr[w+1];
    int e = e0;
    for (; e + 3 < e1; e += 4){
      float v0 = cval[e], v1 = cval[e+1], v2 = cval[e+2], v3 = cval[e+3];
      frag8 x0 = *(const frag8*)(X + (size_t)ccol[e  ]*STR + lane*8);
      frag8 x1 = *(const frag8*)(X + (size_t)ccol[e+1]*STR + lane*8);
      frag8 x2 = *(const frag8*)(X + (size_t)ccol[e+2]*STR + lane*8);
      frag8 x3 = *(const frag8*)(X + (size_t)ccol[e+3]*STR + lane*8);
      #pragma unroll
      for (int j=0;j<8;++j)
        acc[j] += v0*bfs2f(x0[j]) + v1*bfs2f(x1[j]) + v2*bfs2f(x2[j]) + v3*bfs2f(x3[j]);
    }
    for (; e < e1; ++e){
      float v0 = cval[e];
      frag8 x0 = *(const frag8*)(X + (size_t)ccol[e]*STR + lane*8);
      #pragma unroll
      for (int j=0;j<8;++j) acc[j] += v0*bfs2f(x0[j]);
    }
  }
  frag8 o;
  #pragma unroll
  for (int j=0;j<8;++j) o[j] = f2bfs(acc[j]);
  *(frag8*)(Y + (size_t)w*STR + lane*8) = o;
}

// ---------------- node GEMM (MFMA): C = sigmoid(A @ W), pads zeroed ----------------
// grid = (NPAD/128, NVR/128)  [2-D grid: 2745 independent blocks — R8's 1-D loop
// traded TLP for L2 locality and regressed; this kernel is latency/TLP-bound]

__global__ __launch_bounds__(256) void k_gemm_node(const bf16* __restrict__ A,
                                                   const bf16* __restrict__ Wt,
                                                   bf16* __restrict__ C){
  __shared__ bf16 As[128*32];
  __shared__ bf16 Bs[128*32];
  const int tid  = threadIdx.x;
  const int wv   = tid >> 6;
  const int lane = tid & 63;
  const int row0 = blockIdx.y * 128;
  const int n0   = blockIdx.x * 128;
  const int wm = wv & 1, wn = wv >> 1;
  const int srow = lane >> 2;
  const int schk = lane & 3;
  const int fr = lane & 15, fq = lane >> 4;

  f32x4 acc[4][4];
  #pragma unroll
  for (int i=0;i<4;++i)
    #pragma unroll
    for (int j=0;j<4;++j) acc[i][j] = (f32x4)(0.0f);

  for (int k0 = 0; k0 < STR; k0 += 32){
    const bf16* ag = A + (size_t)(row0 + wv*16 + srow)*STR + k0 + schk*8;
    gload_lds16(ag,           As + wv*512 + lane*8);
    gload_lds16(ag + 64*STR,  As + 2048 + wv*512 + lane*8);
    const bf16* bg = Wt + (size_t)(n0 + wv*16 + srow)*STR + k0 + schk*8;
    gload_lds16(bg,           Bs + wv*512 + lane*8);
    gload_lds16(bg + 64*STR,  Bs + 2048 + wv*512 + lane*8);
    __syncthreads();
    frag8 a[4], b[4];
    #pragma unroll
    for (int mi=0;mi<4;++mi)
      a[mi] = *(const frag8*)(As + (wm*64 + mi*16 + fr)*32 + fq*8);
    #pragma unroll
    for (int ni=0;ni<4;++ni)
      b[ni] = *(const frag8*)(Bs + (wn*64 + ni*16 + fr)*32 + fq*8);
    #pragma unroll
    for (int mi=0;mi<4;++mi)
      #pragma unroll
      for (int ni=0;ni<4;++ni)
        acc[mi][ni] = __builtin_amdgcn_mfma_f32_16x16x32_bf16(a[mi], b[ni], acc[mi][ni], 0, 0, 0);
    __syncthreads();
  }

  // C/D layout col=lane&15, row=(lane>>4)*4+reg  [m89/m91-verified]
  #pragma unroll
  for (int mi=0;mi<4;++mi){
    int row = row0 + wm*64 + mi*16 + fq*4;
    #pragma unroll
    for (int ni=0;ni<4;++ni){
      int col = n0 + wn*64 + ni*16 + fr;
      if (col < STR){
        bf16* cp = C + (size_t)row*STR + col;
        #pragma unroll
        for (int r=0;r<4;++r){
          float v = (col < EMB) ? sigmoidf_(acc[mi][ni][r]) : 0.0f;
          cp[(size_t)r*STR] = __float2bfloat16(v);
        }
      }
    }
  }
}

// ---------------- FC1 (fused gather): h1 = sigmoid([H2[node], input] @ Wa + ba) ----------------

__global__ __launch_bounds__(256) void k_fc1g(const bf16* __restrict__ H2,
                                              const int* __restrict__ node,
                                              const float* __restrict__ input,
                                              const bf16* __restrict__ Wat,
                                              const float* __restrict__ ba,
                                              bf16* __restrict__ h1){
  __shared__ bf16 As[128*32];
  __shared__ bf16 Bs[128*32];
  const int tid  = threadIdx.x;
  const int wv   = tid >> 6;
  const int lane = tid & 63;
  const int row0 = blockIdx.y * 128;
  const int n0   = blockIdx.x * 128;
  const int wm = wv & 1, wn = wv >> 1;
  const int srow = lane >> 2;
  const int schk = lane & 3;
  const int fr = lane & 15, fq = lane >> 4;

  const int nlo = node[row0 + wv*16 + srow];
  const int nhi = node[row0 + 64 + wv*16 + srow];

  f32x4 acc[4][4];
  #pragma unroll
  for (int i=0;i<4;++i)
    #pragma unroll
    for (int j=0;j<4;++j) acc[i][j] = (f32x4)(0.0f);

  for (int k0 = 0; k0 < FCK; k0 += 32){
    if (k0 < STR){
      gload_lds16(H2 + (size_t)nlo*STR + k0 + schk*8, As + wv*512 + lane*8);
      gload_lds16(H2 + (size_t)nhi*STR + k0 + schk*8, As + 2048 + wv*512 + lane*8);
    } else {
      int c = k0 - STR + schk*8;
      int m0 = wv*16 + srow;
      float4 u0 = *(const float4*)(input + (size_t)(row0+m0)*IN_DIM + c);
      float4 u1 = *(const float4*)(input + (size_t)(row0+m0)*IN_DIM + c + 4);
      frag8 t0;
      t0[0]=f2bfs(u0.x); t0[1]=f2bfs(u0.y); t0[2]=f2bfs(u0.z); t0[3]=f2bfs(u0.w);
      t0[4]=f2bfs(u1.x); t0[5]=f2bfs(u1.y); t0[6]=f2bfs(u1.z); t0[7]=f2bfs(u1.w);
      *(frag8*)(As + m0*32 + schk*8) = t0;
      int m1 = 64 + wv*16 + srow;
      float4 u2 = *(const float4*)(input + (size_t)(row0+m1)*IN_DIM + c);
      float4 u3 = *(const float4*)(input + (size_t)(row0+m1)*IN_DIM + c + 4);
      frag8 t1;
      t1[0]=f2bfs(u2.x); t1[1]=f2bfs(u2.y); t1[2]=f2bfs(u2.z); t1[3]=f2bfs(u2.w);
      t1[4]=f2bfs(u3.x); t1[5]=f2bfs(u3.y); t1[6]=f2bfs(u3.z); t1[7]=f2bfs(u3.w);
      *(frag8*)(As + m1*32 + schk*8) = t1;
    }
    gload_lds16(Wat + (size_t)(n0 + wv*16 + srow)*FCK + k0 + schk*8, Bs + wv*512 + lane*8);
    gload_lds16(Wat + (size_t)(n0 + 64 + wv*16 + srow)*FCK + k0 + schk*8, Bs + 2048 + wv*512 + lane*8);
    __syncthreads();
    frag8 a[4], b[4];
    #pragma unroll
    for (int mi=0;mi<4;++mi)
      a[mi] = *(const frag8*)(As + (wm*64 + mi*16 + fr)*32 + fq*8);
    #pragma unroll
    for (int ni=0;ni<4;++ni)
      b[ni] = *(const frag8*)(Bs + (wn*64 + ni*16 + fr)*32 + fq*8);
    #pragma unroll
    for (int mi=0;mi<4;++mi)
      #pragma unroll
      for (int ni=0;ni<4;++ni)
        acc[mi][ni] = __builtin_amdgcn_mfma_f32_16x16x32_bf16(a[mi], b[ni], acc[mi][ni], 0, 0, 0);
    __syncthreads();
  }

  #pragma unroll
  for (int mi=0;mi<4;++mi){
    int row = row0 + wm*64 + mi*16 + fq*4;
    #pragma unroll
    for (int ni=0;ni<4;++ni){
      int col = n0 + wn*64 + ni*16 + fr;
      float bv = (col < HID) ? ba[col] : 0.0f;
      bf16* cp = h1 + (size_t)row*HPAD + col;
      #pragma unroll
      for (int r=0;r<4;++r)
        cp[(size_t)r*HPAD] = __float2bfloat16(sigmoidf_(acc[mi][ni][r] + bv));
    }
  }
}

// ---------------- FC2+FC3 fused: out = sigmoid(h1@Wb+bb) @ Wc + bc ----------------
// per-row partial dot with Wc reduced across fr lanes (shfl_xor<16), one f32 atomicAdd
// per (row, j, block-col). bc added once by the n0==0 / wn==0 owner. out pre-zeroed.

__global__ __launch_bounds__(256) void k_fc2o(const bf16* __restrict__ A,
                                              const bf16* __restrict__ B,
                                              const float* __restrict__ bb,
                                              const float* __restrict__ Wc,
                                              const float* __restrict__ bc,
                                              float* __restrict__ out){
  __shared__ bf16 As[128*32];
  __shared__ bf16 Bs[128*32];
  const int tid  = threadIdx.x;
  const int wv   = tid >> 6;
  const int lane = tid & 63;
  const int row0 = blockIdx.y * 128;
  const int n0   = blockIdx.x * 128;
  const int wm = wv & 1, wn = wv >> 1;
  const int srow = lane >> 2;
  const int schk = lane & 3;
  const int fr = lane & 15, fq = lane >> 4;

  f32x4 acc[4][4];
  #pragma unroll
  for (int i=0;i<4;++i)
    #pragma unroll
    for (int j=0;j<4;++j) acc[i][j] = (f32x4)(0.0f);

  for (int k0 = 0; k0 < HPAD; k0 += 32){
    const bf16* ag = A + (size_t)(row0 + wv*16 + srow)*HPAD + k0 + schk*8;
    gload_lds16(ag,            As + wv*512 + lane*8);
    gload_lds16(ag + 64*HPAD,  As + 2048 + wv*512 + lane*8);
    const bf16* bg = B + (size_t)(n0 + wv*16 + srow)*HPAD + k0 + schk*8;
    gload_lds16(bg,            Bs + wv*512 + lane*8);
    gload_lds16(bg + 64*HPAD,  Bs + 2048 + wv*512 + lane*8);
    __syncthreads();
    frag8 a[4], b[4];
    #pragma unroll
    for (int mi=0;mi<4;++mi)
      a[mi] = *(const frag8*)(As + (wm*64 + mi*16 + fr)*32 + fq*8);
    #pragma unroll
    for (int ni=0;ni<4;++ni)
      b[ni] = *(const frag8*)(Bs + (wn*64 + ni*16 + fr)*32 + fq*8);
    #pragma unroll
    for (int mi=0;mi<4;++mi)
      #pragma unroll
      for (int ni=0;ni<4;++ni)
        acc[mi][ni] = __builtin_amdgcn_mfma_f32_16x16x32_bf16(a[mi], b[ni], acc[mi][ni], 0, 0, 0);
    __syncthreads();
  }

  #pragma unroll
  for (int mi=0;mi<4;++mi){
    #pragma unroll
    for (int r=0;r<4;++r){
      int row = row0 + wm*64 + mi*16 + fq*4 + r;
      float s0 = 0.0f, s1 = 0.0f;
      #pragma unroll
      for (int ni=0;ni<4;++ni){
        int col = n0 + wn*64 + ni*16 + fr;
        if (col < HID){
          float v = sigmoidf_(acc[mi][ni][r] + bb[col]);
          s0 += v * Wc[col*2+0];
          s1 += v * Wc[col*2+1];
        }
      }
      #pragma unroll
      for (int off=1; off<16; off<<=1){
        s0 += __shfl_xor(s0, off);
        s1 += __shfl_xor(s1, off);
      }
      if (fr == 0){
        if (n0 == 0 && wn == 0){ s0 += bc[0]; s1 += bc[1]; }
        atomicAdd(out + (size_t)row*2 + 0, s0);
        atomicAdd(out + (size_t)row*2 + 1, s1);
      }
    }
  }
}

// ---------------- launch ----------------

extern "C" void kernel_launch(void* const* d_in, const int* in_sizes, int n_in,
                              void* d_out, int out_size, void* d_ws, size_t ws_size,
                              hipStream_t stream){
  const float* input = (const float*)d_in[0];
  const int*   node  = (const int*)d_in[1];
  const int*   erow  = (const int*)d_in[2];
  const int*   ecol  = (const int*)d_in[3];
  const float* H0    = (const float*)d_in[4];
  const float* W1    = (const float*)d_in[5];
  const float* W2    = (const float*)d_in[6];
  const float* Wa    = (const float*)d_in[7];
  const float* ba    = (const float*)d_in[8];
  const float* Wb    = (const float*)d_in[9];
  const float* bb    = (const float*)d_in[10];
  const float* Wc    = (const float*)d_in[11];
  const float* bc    = (const float*)d_in[12];

  char* p = (char*)d_ws;
  auto alloc = [&](size_t bytes)->char*{ char* r = p; p += (bytes + 255) & ~(size_t)255; return r; };
  int*   deg    = (int*)  alloc((size_t)NVX*4);
  float* dinv   = (float*)alloc((size_t)NVX*4);
  int*   rowptr = (int*)  alloc((size_t)(NVX+1)*4);
  int*   cursor = (int*)  alloc((size_t)NVX*4);
  int*   bsum   = (int*)  alloc((size_t)NB*4);
  int*   boff   = (int*)  alloc((size_t)NB*4);
  int*   ccol   = (int*)  alloc((size_t)NEX*4);
  float* cval   = (float*)alloc((size_t)NEX*4);
  bf16*  Xs     = (bf16*) alloc((size_t)NVR*STR*2);   // H0 bf16, later reused as H2
  bf16*  G      = (bf16*) alloc((size_t)NVR*STR*2);   // spmm output
  bf16*  Hb     = (bf16*) alloc((size_t)NVR*STR*2);   // H1
  bf16*  Wt1    = (bf16*) alloc((size_t)NPAD*STR*2);
  bf16*  Wt2    = (bf16*) alloc((size_t)NPAD*STR*2);
  bf16*  Wat    = (bf16*) alloc((size_t)HPAD*FCK*2);
  bf16*  Wbt    = (bf16*) alloc((size_t)HPAD*HPAD*2);
  bf16*  h1     = (bf16*) alloc((size_t)BATCH*HPAD*2);

  hipMemsetAsync(deg, 0, (size_t)NVX*4, stream);
  hipMemsetAsync(d_out, 0, (size_t)out_size*4, stream);
  k_deg     <<<(NEX+255)/256, 256, 0, stream>>>(erow, deg);
  k_partsum <<<NB, 256, 0, stream>>>(deg, dinv, bsum);
  k_scanb   <<<1, 512, 0, stream>>>(bsum, boff, rowptr);
  k_writeptr<<<NB, 256, 0, stream>>>(deg, boff, rowptr, cursor);
  k_scatter <<<(NEX+255)/256, 256, 0, stream>>>(erow, ecol, dinv, cursor, ccol, cval);
  k_prep    <<<(PRE_TOT+255)/256, 256, 0, stream>>>(H0, W1, W2, Wa, Wb, Xs, Wt1, Wt2, Wat, Wbt);

  dim3 ggrid(NPAD/128, NVR/128);

  // layer 1: H1 = sigmoid((LM @ H0) @ W1)
  k_spmm_v   <<<NVR/4, 256, 0, stream>>>(rowptr, ccol, cval, Xs, G);
  k_gemm_node<<<ggrid, 256, 0, stream>>>(G, Wt1, Hb);
  // layer 2: H2 = sigmoid((LM @ H1) @ W2)   (H2 reuses Xs)
  k_spmm_v   <<<NVR/4, 256, 0, stream>>>(rowptr, ccol, cval, Hb, G);
  k_gemm_node<<<ggrid, 256, 0, stream>>>(G, Wt2, Xs);

  // FC stack (FC3 fused into FC2 epilogue)
  k_fc1g<<<dim3(HPAD/128, BATCH/128), 256, 0, stream>>>(Xs, node, input, Wat, ba, h1);
  k_fc2o<<<dim3(HPAD/128, BATCH/128), 256, 0, stream>>>(h1, Wbt, bb, Wc, bc, (float*)d_out);
}

// Round 10
// 438.313 us; speedup vs baseline: 1.3958x; 1.3423x over previous
//
#include <hip/hip_runtime.h>
#include <hip/hip_bf16.h>

typedef __hip_bfloat16 bf16;

#define NVX 117000
#define NEX 468000
#define EMB 300
#define STR 320            // padded K/row stride for bf16 node buffers (pads zeroed)
#define IN_DIM 768
#define BATCH 4096
#define HID 500
#define FCK 1088           // FC1 K: [H2 row 0..319 | input 0..767]
#define HPAD 512           // FC hidden padded
#define NB 458             // scan blocks: ceil(NVX/256)

// backward-sliced active sets: only rows feeding the batch are computed.
// CAP1 bounds |N(S2)| <= sum deg over S2 ~ Poisson(16.1k), 32768 = +128 sigma.
#define CAP1 32768
#define CAP2 4096

// k_prep linear segments (weights only; H0 is gathered in f32 directly)
#define PRE_W12 (384*STR)
#define PRE_WA  (HPAD*FCK)
#define PRE_WB  (HPAD*HPAD)
#define PRE_TOT (2*PRE_W12 + PRE_WA + PRE_WB)

typedef __attribute__((ext_vector_type(8))) short frag8;   // 8 bf16 (4 VGPRs)
typedef __attribute__((ext_vector_type(4))) float f32x4;   // 4 fp32 acc

__device__ __forceinline__ float sigmoidf_(float x){ return 1.0f/(1.0f + __expf(-x)); }
__device__ __forceinline__ float bfs2f(short s){
  return __uint_as_float(((unsigned int)(unsigned short)s) << 16);
}
__device__ __forceinline__ short f2bfs(float f){
  bf16 b = __float2bfloat16(f);
  return *(short*)&b;
}

__device__ __forceinline__ void gload_lds16(const bf16* g, bf16* l){
  __builtin_amdgcn_global_load_lds((const __attribute__((address_space(1))) void*)g,
                                   (__attribute__((address_space(3))) void*)l, 16, 0, 0);
}

// ---------------- graph preprocessing (full graph: deg/dinv/CSR unchanged) ----------------

__global__ void k_deg(const int* __restrict__ erow, int* __restrict__ deg){
  int i = blockIdx.x*blockDim.x + threadIdx.x;
  if (i < NEX) atomicAdd(&deg[erow[i]], 1);
}

__global__ __launch_bounds__(256) void k_partsum(const int* __restrict__ deg,
                                                 float* __restrict__ dinv,
                                                 int* __restrict__ bsum){
  __shared__ int s[256];
  int t = threadIdx.x;
  int i = blockIdx.x*256 + t;
  int d = (i < NVX) ? deg[i] : 0;
  if (i < NVX) dinv[i] = d > 0 ? rsqrtf((float)d) : 0.0f;
  s[t] = d;
  __syncthreads();
  #pragma unroll
  for (int off=128; off; off>>=1){
    if (t < off) s[t] += s[t+off];
    __syncthreads();
  }
  if (t == 0) bsum[blockIdx.x] = s[0];
}

__global__ __launch_bounds__(512) void k_scanb(const int* __restrict__ bsum,
                                               int* __restrict__ boff){
  __shared__ int s[512];
  int t = threadIdx.x;
  int v = (t < NB) ? bsum[t] : 0;
  s[t] = v; __syncthreads();
  #pragma unroll
  for (int off=1; off<512; off<<=1){
    int u = (t>=off) ? s[t-off] : 0;
    __syncthreads();
    s[t] += u;
    __syncthreads();
  }
  if (t < NB) boff[t] = s[t] - v;
}

__global__ __launch_bounds__(256) void k_writeptr(const int* __restrict__ deg,
                                                  const int* __restrict__ boff,
                                                  int* __restrict__ rowptr,
                                                  int* __restrict__ cursor){
  __shared__ int s[256];
  int t = threadIdx.x;
  int i = blockIdx.x*256 + t;
  int v = (i < NVX) ? deg[i] : 0;
  s[t] = v; __syncthreads();
  #pragma unroll
  for (int off=1; off<256; off<<=1){
    int u = (t>=off) ? s[t-off] : 0;
    __syncthreads();
    s[t] += u;
    __syncthreads();
  }
  if (i < NVX){
    int e = boff[blockIdx.x] + s[t] - v;
    rowptr[i] = e;
    cursor[i] = e;
  }
}

__global__ void k_scatter(const int* __restrict__ erow, const int* __restrict__ ecol,
                          const float* __restrict__ dinv, int* __restrict__ cursor,
                          int* __restrict__ ccol, float* __restrict__ cval){
  int i = blockIdx.x*blockDim.x + threadIdx.x;
  if (i < NEX){
    int r = erow[i], c = ecol[i];
    int p = atomicAdd(&cursor[r], 1);
    ccol[p] = c;
    cval[p] = dinv[r]*dinv[c];
  }
}

// ---------------- active-set construction ----------------

// flag2[v]=1 for v in node[]  (layer-2 rows)
__global__ void k_flag2(const int* __restrict__ node, int* __restrict__ flag2){
  int i = blockIdx.x*blockDim.x + threadIdx.x;
  if (i < BATCH) flag2[node[i]] = 1;
}

// flag1[c]=1 for any edge (r,c) with flag2[r]  (layer-1 rows = gather sources of layer 2)
__global__ void k_flag1(const int* __restrict__ erow, const int* __restrict__ ecol,
                        const int* __restrict__ flag2, int* __restrict__ flag1){
  int i = blockIdx.x*blockDim.x + threadIdx.x;
  if (i < NEX && flag2[erow[i]]) flag1[ecol[i]] = 1;
}

// unordered compaction (order irrelevant: row results are position-independent)
__global__ void k_compact(const int* __restrict__ flag1, const int* __restrict__ flag2,
                          int* __restrict__ L1, int* __restrict__ inv1,
                          int* __restrict__ L2, int* __restrict__ inv2,
                          int* __restrict__ counts){
  int v = blockIdx.x*blockDim.x + threadIdx.x;
  if (v >= NVX) return;
  if (flag1[v]){ int idx = atomicAdd(&counts[0], 1); L1[idx] = v; inv1[v] = idx; }
  if (flag2[v]){ int idx = atomicAdd(&counts[1], 1); L2[idx] = v; inv2[v] = idx; }
}

// ---------------- weight prep: bf16, transposed, padded ----------------
// Wat k-mapping: k<300 -> Wa[k], 300..319 -> 0, 320.. -> Wa[k-20]  (FC1 A = [H2row|input])

__global__ __launch_bounds__(256) void k_prep(const float* __restrict__ W1,
                                              const float* __restrict__ W2,
                                              const float* __restrict__ Wa,
                                              const float* __restrict__ Wb,
                                              bf16* __restrict__ Wt1,
                                              bf16* __restrict__ Wt2,
                                              bf16* __restrict__ Wat,
                                              bf16* __restrict__ Wbt){
  long i = (long)blockIdx.x*256 + threadIdx.x;
  if (i < 2*PRE_W12){
    const float* W = (i < PRE_W12) ? W1 : W2;
    bf16* o = (i < PRE_W12) ? Wt1 : Wt2;
    int j = (int)((i < PRE_W12) ? i : i - PRE_W12);
    int n = j / STR, k = j % STR;
    float v = (n < EMB && k < EMB) ? W[k*EMB + n] : 0.0f;
    o[j] = __float2bfloat16(v);
    return;
  }
  i -= 2*PRE_W12;
  if (i < PRE_WA){
    int n = (int)(i / FCK), k = (int)(i % FCK);
    float v = 0.0f;
    if (n < HID){
      if (k < EMB)        v = Wa[(size_t)k*HID + n];
      else if (k >= STR)  v = Wa[(size_t)(k-(STR-EMB))*HID + n];
    }
    Wat[i] = __float2bfloat16(v);
    return;
  }
  i -= PRE_WA;
  if (i < PRE_WB){
    int n = (int)(i / HPAD), k = (int)(i % HPAD);
    float v = (n < HID && k < HID) ? Wb[(size_t)k*HID + n] : 0.0f;
    Wbt[i] = __float2bfloat16(v);
  }
}

// ---------------- spmm layer 1 (compacted, f32 H0 gather) ----------------
// wave per active row i < counts[0]; rows [n1, n1pad128) zero-filled for MFMA tiles.

__global__ __launch_bounds__(256) void k_spmm1(const int* __restrict__ rowptr,
                                               const int* __restrict__ ccol,
                                               const float* __restrict__ cval,
                                               const float* __restrict__ H0,
                                               const int* __restrict__ L1,
                                               const int* __restrict__ counts,
                                               bf16* __restrict__ Gc1){
  int i = (int)((blockIdx.x*blockDim.x + threadIdx.x) >> 6);
  int lane = threadIdx.x & 63;
  if (lane >= 40) return;
  int n1 = counts[0];
  int n1pad = (n1 + 127) & ~127;
  if (i >= n1pad) return;
  int c0 = lane*8;
  bool hv1 = (c0 + 3) < EMB;   // lanes 0..37 first float4 valid
  bool hv2 = (c0 + 7) < EMB;   // lanes 0..36 second float4 valid
  float acc[8] = {0.f,0.f,0.f,0.f,0.f,0.f,0.f,0.f};
  if (i < n1 && hv1){
    int v = L1[i];
    int e0 = rowptr[v], e1 = rowptr[v+1];
    int e = e0;
    for (; e + 1 < e1; e += 2){
      float va = cval[e], vb = cval[e+1];
      const float* xa = H0 + (size_t)ccol[e  ]*EMB + c0;
      const float* xb = H0 + (size_t)ccol[e+1]*EMB + c0;
      float4 a0 = *(const float4*)xa;
      float4 b0 = *(const float4*)xb;
      float4 a1 = hv2 ? *(const float4*)(xa+4) : make_float4(0,0,0,0);
      float4 b1 = hv2 ? *(const float4*)(xb+4) : make_float4(0,0,0,0);
      acc[0] += va*a0.x + vb*b0.x;  acc[1] += va*a0.y + vb*b0.y;
      acc[2] += va*a0.z + vb*b0.z;  acc[3] += va*a0.w + vb*b0.w;
      acc[4] += va*a1.x + vb*b1.x;  acc[5] += va*a1.y + vb*b1.y;
      acc[6] += va*a1.z + vb*b1.z;  acc[7] += va*a1.w + vb*b1.w;
    }
    if (e < e1){
      float va = cval[e];
      const float* xa = H0 + (size_t)ccol[e]*EMB + c0;
      float4 a0 = *(const float4*)xa;
      float4 a1 = hv2 ? *(const float4*)(xa+4) : make_float4(0,0,0,0);
      acc[0] += va*a0.x; acc[1] += va*a0.y; acc[2] += va*a0.z; acc[3] += va*a0.w;
      acc[4] += va*a1.x; acc[5] += va*a1.y; acc[6] += va*a1.z; acc[7] += va*a1.w;
    }
  }
  frag8 o;
  #pragma unroll
  for (int j=0;j<8;++j) o[j] = f2bfs(acc[j]);
  *(frag8*)(Gc1 + (size_t)i*STR + c0) = o;
}

// ---------------- spmm layer 2 (compacted, bf16 gather from compacted H1) ----------------

__global__ __launch_bounds__(256) void k_spmm2(const int* __restrict__ rowptr,
                                               const int* __restrict__ ccol,
                                               const float* __restrict__ cval,
                                               const bf16* __restrict__ Hc1,
                                               const int* __restrict__ inv1,
                                               const int* __restrict__ L2,
                                               const int* __restrict__ counts,
                                               bf16* __restrict__ Gc2){
  int i = (int)((blockIdx.x*blockDim.x + threadIdx.x) >> 6);
  int lane = threadIdx.x & 63;
  if (lane >= 40) return;
  int n2 = counts[1];
  int n2pad = (n2 + 127) & ~127;
  if (i >= n2pad) return;
  float acc[8] = {0.f,0.f,0.f,0.f,0.f,0.f,0.f,0.f};
  if (i < n2){
    int v = L2[i];
    int e0 = rowptr[v], e1 = rowptr[v+1];
    int e = e0;
    for (; e + 1 < e1; e += 2){
      float va = cval[e], vb = cval[e+1];
      frag8 xa = *(const frag8*)(Hc1 + (size_t)inv1[ccol[e  ]]*STR + lane*8);
      frag8 xb = *(const frag8*)(Hc1 + (size_t)inv1[ccol[e+1]]*STR + lane*8);
      #pragma unroll
      for (int j=0;j<8;++j) acc[j] += va*bfs2f(xa[j]) + vb*bfs2f(xb[j]);
    }
    if (e < e1){
      float va = cval[e];
      frag8 xa = *(const frag8*)(Hc1 + (size_t)inv1[ccol[e]]*STR + lane*8);
      #pragma unroll
      for (int j=0;j<8;++j) acc[j] += va*bfs2f(xa[j]);
    }
  }
  frag8 o;
  #pragma unroll
  for (int j=0;j<8;++j) o[j] = f2bfs(acc[j]);
  *(frag8*)(Gc2 + (size_t)i*STR + lane*8) = o;
}

// ---------------- node GEMM (MFMA): C = sigmoid(A @ W), runtime row count ----------------
// grid = (3, CAP/128); blocks with row0 >= counts[which] exit. Pad rows carry zeros in A
// (spmm zero-fill) -> harmless 0.5s written at pad rows, never read (inv < count).

__global__ __launch_bounds__(256) void k_gemm_node(const bf16* __restrict__ A,
                                                   const bf16* __restrict__ Wt,
                                                   bf16* __restrict__ C,
                                                   const int* __restrict__ counts, int which){
  const int row0 = blockIdx.y * 128;
  if (row0 >= counts[which]) return;
  __shared__ bf16 As[128*32];
  __shared__ bf16 Bs[128*32];
  const int tid  = threadIdx.x;
  const int wv   = tid >> 6;
  const int lane = tid & 63;
  const int n0   = blockIdx.x * 128;
  const int wm = wv & 1, wn = wv >> 1;
  const int srow = lane >> 2;
  const int schk = lane & 3;
  const int fr = lane & 15, fq = lane >> 4;

  f32x4 acc[4][4];
  #pragma unroll
  for (int i=0;i<4;++i)
    #pragma unroll
    for (int j=0;j<4;++j) acc[i][j] = (f32x4)(0.0f);

  for (int k0 = 0; k0 < STR; k0 += 32){
    const bf16* ag = A + (size_t)(row0 + wv*16 + srow)*STR + k0 + schk*8;
    gload_lds16(ag,           As + wv*512 + lane*8);
    gload_lds16(ag + 64*STR,  As + 2048 + wv*512 + lane*8);
    const bf16* bg = Wt + (size_t)(n0 + wv*16 + srow)*STR + k0 + schk*8;
    gload_lds16(bg,           Bs + wv*512 + lane*8);
    gload_lds16(bg + 64*STR,  Bs + 2048 + wv*512 + lane*8);
    __syncthreads();
    frag8 a[4], b[4];
    #pragma unroll
    for (int mi=0;mi<4;++mi)
      a[mi] = *(const frag8*)(As + (wm*64 + mi*16 + fr)*32 + fq*8);
    #pragma unroll
    for (int ni=0;ni<4;++ni)
      b[ni] = *(const frag8*)(Bs + (wn*64 + ni*16 + fr)*32 + fq*8);
    #pragma unroll
    for (int mi=0;mi<4;++mi)
      #pragma unroll
      for (int ni=0;ni<4;++ni)
        acc[mi][ni] = __builtin_amdgcn_mfma_f32_16x16x32_bf16(a[mi], b[ni], acc[mi][ni], 0, 0, 0);
    __syncthreads();
  }

  // C/D layout col=lane&15, row=(lane>>4)*4+reg  [m89/m91-verified]
  #pragma unroll
  for (int mi=0;mi<4;++mi){
    int row = row0 + wm*64 + mi*16 + fq*4;
    #pragma unroll
    for (int ni=0;ni<4;++ni){
      int col = n0 + wn*64 + ni*16 + fr;
      if (col < STR){
        bf16* cp = C + (size_t)row*STR + col;
        #pragma unroll
        for (int r=0;r<4;++r){
          float v = (col < EMB) ? sigmoidf_(acc[mi][ni][r]) : 0.0f;
          cp[(size_t)r*STR] = __float2bfloat16(v);
        }
      }
    }
  }
}

// ---------------- FC1 (fused gather via inv2): h1 = sigmoid([H2[node], input] @ Wa + ba) ----------------

__global__ __launch_bounds__(256) void k_fc1g(const bf16* __restrict__ Hc2,
                                              const int* __restrict__ node,
                                              const int* __restrict__ inv2,
                                              const float* __restrict__ input,
                                              const bf16* __restrict__ Wat,
                                              const float* __restrict__ ba,
                                              bf16* __restrict__ h1){
  __shared__ bf16 As[128*32];
  __shared__ bf16 Bs[128*32];
  const int tid  = threadIdx.x;
  const int wv   = tid >> 6;
  const int lane = tid & 63;
  const int row0 = blockIdx.y * 128;
  const int n0   = blockIdx.x * 128;
  const int wm = wv & 1, wn = wv >> 1;
  const int srow = lane >> 2;
  const int schk = lane & 3;
  const int fr = lane & 15, fq = lane >> 4;

  const int nlo = inv2[node[row0 + wv*16 + srow]];
  const int nhi = inv2[node[row0 + 64 + wv*16 + srow]];

  f32x4 acc[4][4];
  #pragma unroll
  for (int i=0;i<4;++i)
    #pragma unroll
    for (int j=0;j<4;++j) acc[i][j] = (f32x4)(0.0f);

  for (int k0 = 0; k0 < FCK; k0 += 32){
    if (k0 < STR){
      gload_lds16(Hc2 + (size_t)nlo*STR + k0 + schk*8, As + wv*512 + lane*8);
      gload_lds16(Hc2 + (size_t)nhi*STR + k0 + schk*8, As + 2048 + wv*512 + lane*8);
    } else {
      int c = k0 - STR + schk*8;
      int m0 = wv*16 + srow;
      float4 u0 = *(const float4*)(input + (size_t)(row0+m0)*IN_DIM + c);
      float4 u1 = *(const float4*)(input + (size_t)(row0+m0)*IN_DIM + c + 4);
      frag8 t0;
      t0[0]=f2bfs(u0.x); t0[1]=f2bfs(u0.y); t0[2]=f2bfs(u0.z); t0[3]=f2bfs(u0.w);
      t0[4]=f2bfs(u1.x); t0[5]=f2bfs(u1.y); t0[6]=f2bfs(u1.z); t0[7]=f2bfs(u1.w);
      *(frag8*)(As + m0*32 + schk*8) = t0;
      int m1 = 64 + wv*16 + srow;
      float4 u2 = *(const float4*)(input + (size_t)(row0+m1)*IN_DIM + c);
      float4 u3 = *(const float4*)(input + (size_t)(row0+m1)*IN_DIM + c + 4);
      frag8 t1;
      t1[0]=f2bfs(u2.x); t1[1]=f2bfs(u2.y); t1[2]=f2bfs(u2.z); t1[3]=f2bfs(u2.w);
      t1[4]=f2bfs(u3.x); t1[5]=f2bfs(u3.y); t1[6]=f2bfs(u3.z); t1[7]=f2bfs(u3.w);
      *(frag8*)(As + m1*32 + schk*8) = t1;
    }
    gload_lds16(Wat + (size_t)(n0 + wv*16 + srow)*FCK + k0 + schk*8, Bs + wv*512 + lane*8);
    gload_lds16(Wat + (size_t)(n0 + 64 + wv*16 + srow)*FCK + k0 + schk*8, Bs + 2048 + wv*512 + lane*8);
    __syncthreads();
    frag8 a[4], b[4];
    #pragma unroll
    for (int mi=0;mi<4;++mi)
      a[mi] = *(const frag8*)(As + (wm*64 + mi*16 + fr)*32 + fq*8);
    #pragma unroll
    for (int ni=0;ni<4;++ni)
      b[ni] = *(const frag8*)(Bs + (wn*64 + ni*16 + fr)*32 + fq*8);
    #pragma unroll
    for (int mi=0;mi<4;++mi)
      #pragma unroll
      for (int ni=0;ni<4;++ni)
        acc[mi][ni] = __builtin_amdgcn_mfma_f32_16x16x32_bf16(a[mi], b[ni], acc[mi][ni], 0, 0, 0);
    __syncthreads();
  }

  #pragma unroll
  for (int mi=0;mi<4;++mi){
    int row = row0 + wm*64 + mi*16 + fq*4;
    #pragma unroll
    for (int ni=0;ni<4;++ni){
      int col = n0 + wn*64 + ni*16 + fr;
      float bv = (col < HID) ? ba[col] : 0.0f;
      bf16* cp = h1 + (size_t)row*HPAD + col;
      #pragma unroll
      for (int r=0;r<4;++r)
        cp[(size_t)r*HPAD] = __float2bfloat16(sigmoidf_(acc[mi][ni][r] + bv));
    }
  }
}

// ---------------- FC2+FC3 fused: out = sigmoid(h1@Wb+bb) @ Wc + bc ----------------

__global__ __launch_bounds__(256) void k_fc2o(const bf16* __restrict__ A,
                                              const bf16* __restrict__ B,
                                              const float* __restrict__ bb,
                                              const float* __restrict__ Wc,
                                              const float* __restrict__ bc,
                                              float* __restrict__ out){
  __shared__ bf16 As[128*32];
  __shared__ bf16 Bs[128*32];
  const int tid  = threadIdx.x;
  const int wv   = tid >> 6;
  const int lane = tid & 63;
  const int row0 = blockIdx.y * 128;
  const int n0   = blockIdx.x * 128;
  const int wm = wv & 1, wn = wv >> 1;
  const int srow = lane >> 2;
  const int schk = lane & 3;
  const int fr = lane & 15, fq = lane >> 4;

  f32x4 acc[4][4];
  #pragma unroll
  for (int i=0;i<4;++i)
    #pragma unroll
    for (int j=0;j<4;++j) acc[i][j] = (f32x4)(0.0f);

  for (int k0 = 0; k0 < HPAD; k0 += 32){
    const bf16* ag = A + (size_t)(row0 + wv*16 + srow)*HPAD + k0 + schk*8;
    gload_lds16(ag,            As + wv*512 + lane*8);
    gload_lds16(ag + 64*HPAD,  As + 2048 + wv*512 + lane*8);
    const bf16* bg = B + (size_t)(n0 + wv*16 + srow)*HPAD + k0 + schk*8;
    gload_lds16(bg,            Bs + wv*512 + lane*8);
    gload_lds16(bg + 64*HPAD,  Bs + 2048 + wv*512 + lane*8);
    __syncthreads();
    frag8 a[4], b[4];
    #pragma unroll
    for (int mi=0;mi<4;++mi)
      a[mi] = *(const frag8*)(As + (wm*64 + mi*16 + fr)*32 + fq*8);
    #pragma unroll
    for (int ni=0;ni<4;++ni)
      b[ni] = *(const frag8*)(Bs + (wn*64 + ni*16 + fr)*32 + fq*8);
    #pragma unroll
    for (int mi=0;mi<4;++mi)
      #pragma unroll
      for (int ni=0;ni<4;++ni)
        acc[mi][ni] = __builtin_amdgcn_mfma_f32_16x16x32_bf16(a[mi], b[ni], acc[mi][ni], 0, 0, 0);
    __syncthreads();
  }

  #pragma unroll
  for (int mi=0;mi<4;++mi){
    #pragma unroll
    for (int r=0;r<4;++r){
      int row = row0 + wm*64 + mi*16 + fq*4 + r;
      float s0 = 0.0f, s1 = 0.0f;
      #pragma unroll
      for (int ni=0;ni<4;++ni){
        int col = n0 + wn*64 + ni*16 + fr;
        if (col < HID){
          float v = sigmoidf_(acc[mi][ni][r] + bb[col]);
          s0 += v * Wc[col*2+0];
          s1 += v * Wc[col*2+1];
        }
      }
      #pragma unroll
      for (int off=1; off<16; off<<=1){
        s0 += __shfl_xor(s0, off);
        s1 += __shfl_xor(s1, off);
      }
      if (fr == 0){
        if (n0 == 0 && wn == 0){ s0 += bc[0]; s1 += bc[1]; }
        atomicAdd(out + (size_t)row*2 + 0, s0);
        atomicAdd(out + (size_t)row*2 + 1, s1);
      }
    }
  }
}

// ---------------- launch ----------------

extern "C" void kernel_launch(void* const* d_in, const int* in_sizes, int n_in,
                              void* d_out, int out_size, void* d_ws, size_t ws_size,
                              hipStream_t stream){
  const float* input = (const float*)d_in[0];
  const int*   node  = (const int*)d_in[1];
  const int*   erow  = (const int*)d_in[2];
  const int*   ecol  = (const int*)d_in[3];
  const float* H0    = (const float*)d_in[4];
  const float* W1    = (const float*)d_in[5];
  const float* W2    = (const float*)d_in[6];
  const float* Wa    = (const float*)d_in[7];
  const float* ba    = (const float*)d_in[8];
  const float* Wb    = (const float*)d_in[9];
  const float* bb    = (const float*)d_in[10];
  const float* Wc    = (const float*)d_in[11];
  const float* bc    = (const float*)d_in[12];

  char* p = (char*)d_ws;
  auto alloc = [&](size_t bytes)->char*{ char* r = p; p += (bytes + 255) & ~(size_t)255; return r; };
  // zero-region (one memset): deg, flag1, flag2, counts
  char* z0     = p;
  int*   deg    = (int*)  alloc((size_t)NVX*4);
  int*   flag1  = (int*)  alloc((size_t)NVX*4);
  int*   flag2  = (int*)  alloc((size_t)NVX*4);
  int*   counts = (int*)  alloc(256);
  size_t zlen   = (size_t)(p - z0);
  float* dinv   = (float*)alloc((size_t)NVX*4);
  int*   rowptr = (int*)  alloc((size_t)(NVX+1)*4);
  int*   cursor = (int*)  alloc((size_t)NVX*4);
  int*   bsum   = (int*)  alloc((size_t)NB*4);
  int*   boff   = (int*)  alloc((size_t)NB*4);
  int*   ccol   = (int*)  alloc((size_t)NEX*4);
  float* cval   = (float*)alloc((size_t)NEX*4);
  int*   L1     = (int*)  alloc((size_t)CAP1*4);
  int*   inv1   = (int*)  alloc((size_t)NVX*4);
  int*   L2     = (int*)  alloc((size_t)CAP2*4);
  int*   inv2   = (int*)  alloc((size_t)NVX*4);
  bf16*  Gc1    = (bf16*) alloc((size_t)CAP1*STR*2);
  bf16*  Hc1    = (bf16*) alloc((size_t)CAP1*STR*2);
  bf16*  Gc2    = (bf16*) alloc((size_t)CAP2*STR*2);
  bf16*  Hc2    = (bf16*) alloc((size_t)CAP2*STR*2);
  bf16*  Wt1    = (bf16*) alloc((size_t)384*STR*2);
  bf16*  Wt2    = (bf16*) alloc((size_t)384*STR*2);
  bf16*  Wat    = (bf16*) alloc((size_t)HPAD*FCK*2);
  bf16*  Wbt    = (bf16*) alloc((size_t)HPAD*HPAD*2);
  bf16*  h1     = (bf16*) alloc((size_t)BATCH*HPAD*2);

  hipMemsetAsync(z0, 0, zlen, stream);
  hipMemsetAsync(d_out, 0, (size_t)out_size*4, stream);

  // full-graph CSR (needed for edge iteration of active rows)
  k_deg     <<<(NEX+255)/256, 256, 0, stream>>>(erow, deg);
  k_partsum <<<NB, 256, 0, stream>>>(deg, dinv, bsum);
  k_scanb   <<<1, 512, 0, stream>>>(bsum, boff);
  k_writeptr<<<NB, 256, 0, stream>>>(deg, boff, rowptr, cursor);
  k_scatter <<<(NEX+255)/256, 256, 0, stream>>>(erow, ecol, dinv, cursor, ccol, cval);

  // active sets (backward slice from batch nodes)
  k_flag2  <<<(BATCH+255)/256, 256, 0, stream>>>(node, flag2);
  k_flag1  <<<(NEX+255)/256, 256, 0, stream>>>(erow, ecol, flag2, flag1);
  k_compact<<<(NVX+255)/256, 256, 0, stream>>>(flag1, flag2, L1, inv1, L2, inv2, counts);

  // weight prep
  k_prep<<<(PRE_TOT+255)/256, 256, 0, stream>>>(W1, W2, Wa, Wb, Wt1, Wt2, Wat, Wbt);

  // layer 1 (compacted): Hc1 = sigmoid((LM @ H0)[L1] @ W1)
  k_spmm1    <<<CAP1/4, 256, 0, stream>>>(rowptr, ccol, cval, H0, L1, counts, Gc1);
  k_gemm_node<<<dim3(3, CAP1/128), 256, 0, stream>>>(Gc1, Wt1, Hc1, counts, 0);
  // layer 2 (compacted): Hc2 = sigmoid((LM @ H1)[L2] @ W2)
  k_spmm2    <<<CAP2/4, 256, 0, stream>>>(rowptr, ccol, cval, Hc1, inv1, L2, counts, Gc2);
  k_gemm_node<<<dim3(3, CAP2/128), 256, 0, stream>>>(Gc2, Wt2, Hc2, counts, 1);

  // FC stack (FC3 fused into FC2 epilogue)
  k_fc1g<<<dim3(HPAD/128, BATCH/128), 256, 0, stream>>>(Hc2, node, inv2, input, Wat, ba, h1);
  k_fc2o<<<dim3(HPAD/128, BATCH/128), 256, 0, stream>>>(h1, Wbt, bb, Wc, bc, (float*)d_out);
}